// Round 15
// baseline (54.369 us; speedup 1.0000x reference)
//
#include <hip/hip_runtime.h>
#include <hip/hip_bf16.h>

#define KK 32
#define DD 32
#define HH 8
#define NROWS 1024
#define NPTS 262144
#define NNSQ 65536
#define TPB 1024
#define NBLK 256              // 1 block/CU, 1024 points each
#define SLICE_US 8192         // 16KB slice
#define SLOT_US 16384         // phase pair = 32KB
#define IBR 1025              // ibuf row dwords (odd-ish stride)

typedef __attribute__((ext_vector_type(8))) unsigned short ushort8;
typedef __attribute__((ext_vector_type(4))) int iv4;

#define FENCE  asm volatile("" ::: "memory")
#define LGKM0  asm volatile("s_waitcnt lgkmcnt(0)" ::: "memory")
#define BAR    __builtin_amdgcn_s_barrier()
#define VMW(n) asm volatile("s_waitcnt vmcnt(" #n ")" ::: "memory")

__device__ __forceinline__ unsigned short f2bf(float f) {
    unsigned u = __float_as_uint(f);
    unsigned r = (u + 0x7FFFu + ((u >> 16) & 1u)) >> 16;
    return (unsigned short)r;
}

__device__ __forceinline__ void gload16(const void* g, void* l) {
    __builtin_amdgcn_global_load_lds(
        (const __attribute__((address_space(1))) void*)g,
        (__attribute__((address_space(3))) void*)l,
        16, 0, 0);
}

// ---------------------------------------------------------------------------
// Kernel A: proj[k][e-1][h] = sum_d feat[e][d] * W[k][d][h]  (bf16, e=1..1024)
// ---------------------------------------------------------------------------
__global__ __launch_bounds__(256) void build_proj_bf16(
    const float* __restrict__ feat,    // [1025][32]
    const float* __restrict__ w,       // [32][256]
    unsigned short* __restrict__ proj) // [32][1024][8]
{
    int t = blockIdx.x * 256 + threadIdx.x;
    int k = t >> 10;
    int e = (t & 1023) + 1;
    const float* frow = feat + (size_t)e * DD;
    const float* wrow = w + (size_t)k * DD * HH;
    float acc[HH];
#pragma unroll
    for (int h = 0; h < HH; ++h) acc[h] = 0.0f;
#pragma unroll
    for (int d = 0; d < DD; ++d) {
        float f = frow[d];
#pragma unroll
        for (int h = 0; h < HH; ++h) acc[h] = fmaf(f, wrow[d * HH + h], acc[h]);
    }
    ushort8 o;
#pragma unroll
    for (int h = 0; h < HH; ++h) o[h] = f2bf(acc[h]);
    *(ushort8*)(proj + (size_t)t * HH) = o;
}

// ---------------------------------------------------------------------------
// Kernel B v15: wave-specialized producer/consumer.
//  waves 0-13 (896 pts): stage 3-slot gload_lds ring; their vmcnt holds ONLY
//    stage loads -> constant VMW(2|3) per phase, zero idx coupling.
//  waves 14-15 (128 pts + production): stream idx chunks (8 hops x 1024 pts)
//    on their own vmcnt (issue 32, drain VMW(16/8/0)) into triple-buffered
//    ibuf; also gather their own points. Stalls absorbed at the barrier.
// E = ints per index element (2 = int64 input, 1 = int32).
// ---------------------------------------------------------------------------
template <int E>
__global__ __launch_bounds__(TPB) void attn_bias_v15(
    const int* __restrict__ sp,               // [NPTS] (*E)
    const int* __restrict__ ei,               // [NPTS*KK] (*E)
    const float* __restrict__ semb,           // [512][8]
    const unsigned short* __restrict__ proj,  // [32][1024][8] bf16
    float* __restrict__ out)                  // [4][8][NNSQ]
{
    __shared__ __align__(16) unsigned short tbuf[3 * SLOT_US]; // 96KB ring
    __shared__ __align__(16) unsigned short zrow[8];
    __shared__ unsigned ibuf[3][4][IBR];                       // 48.05KB

    const int tid  = threadIdx.x;
    const int w    = tid >> 6;       // wave id 0..15
    const int lane = tid & 63;
    const int pg   = blockIdx.x * TPB + tid;
    const int ptid = tid - 896;      // producer lane id (waves 14,15)

    constexpr int RC = (E == 2) ? 8 : 4;   // iv4 per round per producer thread
    const iv4* EI4 = (const iv4*)ei;
    const size_t bi4 = (size_t)blockIdx.x * TPB * (8 * E);  // iv4s/point = 8E

    iv4 hv[4 * RC];   // producer staging regs (const-indexed via unroll)

    float acc[HH];
#pragma unroll
    for (int h = 0; h < HH; ++h) acc[h] = 0.0f;
    int cnt = 0;
    int sv;

    // ---- producer helpers ----
    auto issueR = [&](int g, int r) {
#pragma unroll
        for (int c = 0; c < RC; ++c) {
            int j = (r * RC + c) * 128 + ptid;
            if constexpr (E == 2) {
                int pt = j >> 2, q = j & 3;
                hv[r * RC + c] = EI4[bi4 + (size_t)pt * 16 + g * 4 + q];
            } else {
                int pt = j >> 1, q = j & 1;
                hv[r * RC + c] = EI4[bi4 + (size_t)pt * 8 + g * 2 + q];
            }
        }
    };
    auto issueC = [&](int g) {
        issueR(g, 0); FENCE; issueR(g, 1); FENCE;
        issueR(g, 2); FENCE; issueR(g, 3); FENCE;
    };
    auto wrR = [&](int b3, int r) {
#pragma unroll
        for (int c = 0; c < RC; ++c) {
            int j = (r * RC + c) * 128 + ptid;
            iv4 v = hv[r * RC + c];
            if constexpr (E == 2) {
                int pt = j >> 2, q = j & 3;
                ibuf[b3][q][pt] = ((unsigned)v.x & 0xffffu) | ((unsigned)v.z << 16);
            } else {
                int pt = j >> 1, q = j & 1;
                ibuf[b3][2 * q    ][pt] = ((unsigned)v.x & 0xffffu) | ((unsigned)v.y << 16);
                ibuf[b3][2 * q + 1][pt] = ((unsigned)v.z & 0xffffu) | ((unsigned)v.w << 16);
            }
        }
    };
#define HV2 do{ if constexpr (E == 2) { VMW(16); } else { VMW(8); } }while(0)
#define HV1 do{ if constexpr (E == 2) { VMW(8);  } else { VMW(4); } }while(0)

    // ---- consumer stage: 32 x 1KB segments over 14 waves ----
    auto stg = [&](int q) {
        int slot = q % 3;
        {
            int seg = w;
            gload16(proj + (size_t)q * SLOT_US + seg * 512 + lane * 8,
                    &tbuf[slot * SLOT_US + seg * 512 + lane * 8]);
        }
        {
            int seg = 14 + w;
            gload16(proj + (size_t)q * SLOT_US + seg * 512 + lane * 8,
                    &tbuf[slot * SLOT_US + seg * 512 + lane * 8]);
        }
        if (w < 4) {
            int seg = 28 + w;
            gload16(proj + (size_t)q * SLOT_US + seg * 512 + lane * 8,
                    &tbuf[slot * SLOT_US + seg * 512 + lane * 8]);
        }
    };
#define CDRAIN do{ if (w < 4) { VMW(3); } else { VMW(2); } }while(0)

    // ---- gather both hops of phase p ----
#define HOP2(p) do{                                                            \
        unsigned pr = ibuf[((p) >> 2) % 3][(p) & 3][tid];                      \
        int e0 = pr & 0xffffu;                                                 \
        int e1 = pr >> 16;                                                     \
        cnt += (e0 != 0) + (e1 != 0);                                          \
        const unsigned short* tb = &tbuf[((p) % 3) * SLOT_US];                 \
        const unsigned short* a0 = e0 ? tb + (e0 - 1) * HH : zrow;             \
        const unsigned short* a1 = e1 ? tb + SLICE_US + (e1 - 1) * HH : zrow;  \
        ushort8 w0 = *(const ushort8*)a0;                                      \
        ushort8 w1 = *(const ushort8*)a1;                                      \
        _Pragma("unroll")                                                      \
        for (int h = 0; h < HH; ++h) {                                         \
            acc[h] += __uint_as_float(((unsigned)w0[h]) << 16);                \
            acc[h] += __uint_as_float(((unsigned)w1[h]) << 16);                \
        }                                                                      \
    }while(0)

    // ---- one phase; single BAR for all waves ----
#define PHASE(p) do{                                                           \
        if (w < 14) {                                                          \
            if ((p) <= 13) stg((p) + 2);                                       \
        } else {                                                               \
            if ((p) % 4 == 0 && (p) <= 8) {                                    \
                HV2; wrR(((p) / 4 + 1) % 3, 0); wrR(((p) / 4 + 1) % 3, 1);     \
            } else if ((p) % 4 == 1 && (p) <= 9) {                             \
                HV1; wrR((((p) - 1) / 4 + 1) % 3, 2);                          \
            } else if ((p) % 4 == 2 && (p) <= 10) {                            \
                VMW(0); wrR((((p) - 2) / 4 + 1) % 3, 3);                       \
            } else if ((p) % 4 == 3 && (p) <= 7) {                             \
                issueC((p) / 4 + 2);                                           \
            }                                                                  \
        }                                                                      \
        HOP2(p);                                                               \
        FENCE;                                                                 \
        if (w < 14) { if ((p) <= 13) { CDRAIN; } else if ((p) == 14) { VMW(0); } } \
        LGKM0;                                                                 \
        BAR;                                                                   \
    }while(0)

    // ---------------- prologue ----------------
    if constexpr (E == 2) sv = (int)((const long long*)sp)[pg];
    else                  sv = sp[pg];
    FENCE;
    if (w < 14) {
        stg(0); stg(1);
    } else {
        issueC(0);
        HV2;    wrR(0, 0); wrR(0, 1);
        HV1;    wrR(0, 2);
        VMW(0); wrR(0, 3);
        issueC(1);
    }
    if (tid == 0) *(float4*)zrow = make_float4(0.f, 0.f, 0.f, 0.f);
    FENCE;
    if (w < 14) CDRAIN;
    LGKM0;
    BAR;

    // ---------------- 16 phases ----------------
    PHASE(0);  PHASE(1);  PHASE(2);  PHASE(3);
    PHASE(4);  PHASE(5);  PHASE(6);  PHASE(7);
    PHASE(8);  PHASE(9);  PHASE(10); PHASE(11);
    PHASE(12); PHASE(13); PHASE(14); PHASE(15);

    // ---------------- epilogue ----------------
    const float4* srow = (const float4*)(semb + (size_t)sv * HH);
    float4 s0v = srow[0], s1v = srow[1];
    float sb[HH] = {s0v.x, s0v.y, s0v.z, s0v.w, s1v.x, s1v.y, s1v.z, s1v.w};

    float inv = 1.0f / (float)(cnt ? cnt : 1);
    float* o = out + (size_t)(pg >> 16) * (HH * NNSQ) + (pg & (NNSQ - 1));
#pragma unroll
    for (int h = 0; h < HH; ++h)
        o[(size_t)h * NNSQ] = sb[h] + acc[h] * inv;
}

extern "C" void kernel_launch(void* const* d_in, const int* in_sizes, int n_in,
                              void* d_out, int out_size, void* d_ws, size_t ws_size,
                              hipStream_t stream) {
    const int*   sp = (const int*)d_in[0];    // spatial_pos  [4,256,256]
    const int*   ei = (const int*)d_in[1];    // edge_input   [4,256,256,32]
    const float* se = (const float*)d_in[2];  // spatial_emb  [512,8]
    const float* fe = (const float*)d_in[3];  // edge_feat_emb[1025,32]
    const float* pw = (const float*)d_in[4];  // edge_pos_emb [32,256]
    float* out = (float*)d_out;

    const bool i64 = (in_sizes[0] == 2 * NPTS);
    unsigned short* proj = (unsigned short*)d_ws;   // 512KB

    build_proj_bf16<<<128, 256, 0, stream>>>(fe, pw, proj);

    if (i64) attn_bias_v15<2><<<NBLK, TPB, 0, stream>>>(sp, ei, se, proj, out);
    else     attn_bias_v15<1><<<NBLK, TPB, 0, stream>>>(sp, ei, se, proj, out);
}